// Round 2
// baseline (840.894 us; speedup 1.0000x reference)
//
#include <hip/hip_runtime.h>
#include <math.h>

// NNUE forward, all tensors float32 (reference is f32 end-to-end).
// B=8192, N_IN=12288, H0=256, H1=H2=32.
// Features are 0/1 f32 with ~0.25% density -> sparse gather-sum of ft_w columns.
// Floor: streaming 2 x 402 MB of feature data from HBM (~128 us at 6.3 TB/s).

#define NIN   12288
#define NF4   3072   // NIN / 4 floats per float4
#define FPT   12     // NF4 / 256 threads
#define H0    256
#define MAXF  192    // active-feature list cap (expected ~31)

// ft_w (256 x 12288) -> ft_w_T (12288 x 256), f32, LDS-tiled (coalesced both sides).
__global__ __launch_bounds__(256) void transpose_ftw(const float* __restrict__ src,
                                                     float* __restrict__ dst) {
    __shared__ float tile[32][33];
    const int jb = blockIdx.x * 32;      // input-feature tile base
    const int hb = blockIdx.y * 32;      // hidden-unit tile base
    const int tx = threadIdx.x;          // 0..31
    const int ty = threadIdx.y;          // 0..7
#pragma unroll
    for (int r = 0; r < 32; r += 8)
        tile[ty + r][tx] = src[(size_t)(hb + ty + r) * NIN + jb + tx];
    __syncthreads();
#pragma unroll
    for (int r = 0; r < 32; r += 8)
        dst[(size_t)(jb + ty + r) * H0 + hb + tx] = tile[tx][ty + r];
}

template <bool TRANSPOSED>
__global__ __launch_bounds__(256) void nnue_kernel(
    const float* __restrict__ white,     // (B, NIN)
    const float* __restrict__ black,
    const int* __restrict__ side,        // (B,)
    const float* __restrict__ ftw,       // TRANSPOSED ? (NIN,256) : (256,NIN)
    const float* __restrict__ ft_b,      // (256,)
    const float* __restrict__ l1_w,      // (32,512)
    const float* __restrict__ l1_b,      // (32,)
    const float* __restrict__ l2_w,      // (32,32)
    const float* __restrict__ l2_b,      // (32,)
    const float* __restrict__ l3_w,      // (32,)
    const float* __restrict__ l3_b,      // (1,)
    float* __restrict__ out)             // (B,)
{
    __shared__ int w_list[MAXF];
    __shared__ int b_list[MAXF];
    __shared__ int w_cnt, b_cnt;
    __shared__ float sh_o0[512] __attribute__((aligned(16)));
    __shared__ float sh_o1[32];
    __shared__ float sh_o2[32];

    const int s   = blockIdx.x;
    const int tid = threadIdx.x;

    if (tid == 0) { w_cnt = 0; b_cnt = 0; }
    __syncthreads();

    // ---- Phase 1: stream both feature rows, collect nonzero indices ----
    // Values are exactly 0.0f or 1.0f -> integer-compare the raw words.
    const uint4* wrow = (const uint4*)(white + (size_t)s * NIN);
    const uint4* brow = (const uint4*)(black + (size_t)s * NIN);
#pragma unroll
    for (int i = 0; i < FPT; ++i) {
        const int v = i * 256 + tid;     // float4 index within row (coalesced)
        uint4 u = wrow[v];
        if (u.x | u.y | u.z | u.w) {
            if (u.x) { int p = atomicAdd(&w_cnt, 1); if (p < MAXF) w_list[p] = v * 4 + 0; }
            if (u.y) { int p = atomicAdd(&w_cnt, 1); if (p < MAXF) w_list[p] = v * 4 + 1; }
            if (u.z) { int p = atomicAdd(&w_cnt, 1); if (p < MAXF) w_list[p] = v * 4 + 2; }
            if (u.w) { int p = atomicAdd(&w_cnt, 1); if (p < MAXF) w_list[p] = v * 4 + 3; }
        }
        uint4 ub = brow[v];
        if (ub.x | ub.y | ub.z | ub.w) {
            if (ub.x) { int p = atomicAdd(&b_cnt, 1); if (p < MAXF) b_list[p] = v * 4 + 0; }
            if (ub.y) { int p = atomicAdd(&b_cnt, 1); if (p < MAXF) b_list[p] = v * 4 + 1; }
            if (ub.z) { int p = atomicAdd(&b_cnt, 1); if (p < MAXF) b_list[p] = v * 4 + 2; }
            if (ub.w) { int p = atomicAdd(&b_cnt, 1); if (p < MAXF) b_list[p] = v * 4 + 3; }
        }
    }
    __syncthreads();

    const int wn = min(w_cnt, MAXF);
    const int bn = min(b_cnt, MAXF);

    // ---- Phase 2: gather-sum ft_w columns; thread t owns hidden unit h=t ----
    const float bias = ft_b[tid];
    float wacc = bias;
    float bacc = bias;
    for (int k = 0; k < wn; ++k) {
        const int j = w_list[k];
        wacc += TRANSPOSED ? ftw[(size_t)j * H0 + tid] : ftw[(size_t)tid * NIN + j];
    }
    for (int k = 0; k < bn; ++k) {
        const int j = b_list[k];
        bacc += TRANSPOSED ? ftw[(size_t)j * H0 + tid] : ftw[(size_t)tid * NIN + j];
    }
    const float ow = fminf(fmaxf(wacc, 0.f), 1.f);
    const float ob = fminf(fmaxf(bacc, 0.f), 1.f);
    const bool sd = (side[s] != 0);
    sh_o0[tid]       = sd ? ow : ob;
    sh_o0[256 + tid] = sd ? ob : ow;
    __syncthreads();

    // ---- l1: (32,512) @ o0 ; 8 threads per output row, 64 elems each ----
    {
        const int o = tid >> 3;   // 0..31
        const int p = tid & 7;    // 0..7
        const float4* wp = (const float4*)(l1_w + (o * 512 + p * 64));
        const float4* xp = (const float4*)(sh_o0 + p * 64);
        float sum = 0.f;
#pragma unroll
        for (int v = 0; v < 16; ++v) {
            float4 w4 = wp[v];
            float4 x4 = xp[v];
            sum += w4.x * x4.x + w4.y * x4.y + w4.z * x4.z + w4.w * x4.w;
        }
        sum += __shfl_down(sum, 4, 8);
        sum += __shfl_down(sum, 2, 8);
        sum += __shfl_down(sum, 1, 8);
        if (p == 0) sh_o1[o] = fminf(fmaxf(sum + l1_b[o], 0.f), 1.f);
    }
    __syncthreads();

    // ---- l2: (32,32) ----
    if (tid < 32) {
        float sum = 0.f;
#pragma unroll
        for (int k = 0; k < 32; ++k) sum += l2_w[tid * 32 + k] * sh_o1[k];
        sh_o2[tid] = fminf(fmaxf(sum + l2_b[tid], 0.f), 1.f);
    }
    __syncthreads();

    // ---- l3 + sigmoid ----
    if (tid < 32) {
        float p = l3_w[tid] * sh_o2[tid];
        p += __shfl_down(p, 16, 32);
        p += __shfl_down(p, 8, 32);
        p += __shfl_down(p, 4, 32);
        p += __shfl_down(p, 2, 32);
        p += __shfl_down(p, 1, 32);
        if (tid == 0) {
            const float o3  = (p + l3_b[0]) * 300.0f;
            const float sig = 1.0f / (1.0f + expf(-o3 / 200.0f));
            out[s] = sig;
        }
    }
}

extern "C" void kernel_launch(void* const* d_in, const int* in_sizes, int n_in,
                              void* d_out, int out_size, void* d_ws, size_t ws_size,
                              hipStream_t stream) {
    const float* white = (const float*)d_in[0];
    const float* black = (const float*)d_in[1];
    const int*   side  = (const int*)d_in[2];
    const float* ft_w  = (const float*)d_in[3];
    const float* ft_b  = (const float*)d_in[4];
    const float* l1_w  = (const float*)d_in[5];
    const float* l1_b  = (const float*)d_in[6];
    const float* l2_w  = (const float*)d_in[7];
    const float* l2_b  = (const float*)d_in[8];
    const float* l3_w  = (const float*)d_in[9];
    const float* l3_b  = (const float*)d_in[10];
    float*       out   = (float*)d_out;

    const int B = in_sizes[2];  // 8192
    const size_t t_bytes = (size_t)NIN * H0 * sizeof(float);  // 12.6 MB

    if (ws_size >= t_bytes) {
        float* ftw_t = (float*)d_ws;
        hipLaunchKernelGGL(transpose_ftw, dim3(NIN / 32, H0 / 32), dim3(32, 8), 0, stream,
                           ft_w, ftw_t);
        hipLaunchKernelGGL((nnue_kernel<true>), dim3(B), dim3(256), 0, stream,
                           white, black, side, ftw_t, ft_b, l1_w, l1_b, l2_w, l2_b, l3_w, l3_b, out);
    } else {
        hipLaunchKernelGGL((nnue_kernel<false>), dim3(B), dim3(256), 0, stream,
                           white, black, side, ft_w, ft_b, l1_w, l1_b, l2_w, l2_b, l3_w, l3_b, out);
    }
}

// Round 3
// 824.997 us; speedup vs baseline: 1.0193x; 1.0193x over previous
//
#include <hip/hip_runtime.h>
#include <math.h>

// NNUE forward, all tensors float32. B=8192, N_IN=12288, H0=256, H1=H2=32.
// Features are 0/1 f32, ~0.25% density -> sparse gather-sum of ft_w^T columns.
// Floor: streaming 805 MB of feature data (~128 us at 6.3 TB/s).
// R3: register-batched feature loads (memory-level parallelism), 4-wide gather
// ILP, bank-conflict-free l1 via p-staggered LDS reads.

#define NIN   12288
#define NF4   3072   // NIN / 4 floats per float4
#define FPT   12     // NF4 / 256 threads
#define H0    256
#define MAXF  192    // active-feature list cap (expected ~31)

// ft_w (256 x 12288) -> ft_w_T (12288 x 256), f32, LDS-tiled.
__global__ __launch_bounds__(256) void transpose_ftw(const float* __restrict__ src,
                                                     float* __restrict__ dst) {
    __shared__ float tile[32][33];
    const int jb = blockIdx.x * 32;
    const int hb = blockIdx.y * 32;
    const int tx = threadIdx.x;
    const int ty = threadIdx.y;
#pragma unroll
    for (int r = 0; r < 32; r += 8)
        tile[ty + r][tx] = src[(size_t)(hb + ty + r) * NIN + jb + tx];
    __syncthreads();
#pragma unroll
    for (int r = 0; r < 32; r += 8)
        dst[(size_t)(jb + ty + r) * H0 + hb + tx] = tile[tx][ty + r];
}

template <bool TRANSPOSED>
__global__ __launch_bounds__(256) void nnue_kernel(
    const float* __restrict__ white,     // (B, NIN)
    const float* __restrict__ black,
    const int* __restrict__ side,        // (B,)
    const float* __restrict__ ftw,       // TRANSPOSED ? (NIN,256) : (256,NIN)
    const float* __restrict__ ft_b,      // (256,)
    const float* __restrict__ l1_w,      // (32,512)
    const float* __restrict__ l1_b,      // (32,)
    const float* __restrict__ l2_w,      // (32,32)
    const float* __restrict__ l2_b,      // (32,)
    const float* __restrict__ l3_w,      // (32,)
    const float* __restrict__ l3_b,      // (1,)
    float* __restrict__ out)             // (B,)
{
    __shared__ int w_list[MAXF];
    __shared__ int b_list[MAXF];
    __shared__ int w_cnt, b_cnt;
    __shared__ float sh_o0[512] __attribute__((aligned(16)));
    __shared__ float sh_o1[32];
    __shared__ float sh_o2[32];

    const int s   = blockIdx.x;
    const int tid = threadIdx.x;

    if (tid == 0) { w_cnt = 0; b_cnt = 0; }
    __syncthreads();

    // ---- Phase 1a: issue ALL feature loads into registers (MLP in flight) ----
    const uint4* wrow = (const uint4*)(white + (size_t)s * NIN);
    const uint4* brow = (const uint4*)(black + (size_t)s * NIN);
    uint4 wv[FPT], bv[FPT];
#pragma unroll
    for (int i = 0; i < FPT; ++i) wv[i] = wrow[i * 256 + tid];
#pragma unroll
    for (int i = 0; i < FPT; ++i) bv[i] = brow[i * 256 + tid];

    // ---- Phase 1b: scan registers, collect nonzero indices ----
#pragma unroll
    for (int i = 0; i < FPT; ++i) {
        const int v = i * 256 + tid;
        const uint4 u = wv[i];
        if (u.x | u.y | u.z | u.w) {
            if (u.x) { int p = atomicAdd(&w_cnt, 1); if (p < MAXF) w_list[p] = v * 4 + 0; }
            if (u.y) { int p = atomicAdd(&w_cnt, 1); if (p < MAXF) w_list[p] = v * 4 + 1; }
            if (u.z) { int p = atomicAdd(&w_cnt, 1); if (p < MAXF) w_list[p] = v * 4 + 2; }
            if (u.w) { int p = atomicAdd(&w_cnt, 1); if (p < MAXF) w_list[p] = v * 4 + 3; }
        }
        const uint4 b = bv[i];
        if (b.x | b.y | b.z | b.w) {
            if (b.x) { int p = atomicAdd(&b_cnt, 1); if (p < MAXF) b_list[p] = v * 4 + 0; }
            if (b.y) { int p = atomicAdd(&b_cnt, 1); if (p < MAXF) b_list[p] = v * 4 + 1; }
            if (b.z) { int p = atomicAdd(&b_cnt, 1); if (p < MAXF) b_list[p] = v * 4 + 2; }
            if (b.w) { int p = atomicAdd(&b_cnt, 1); if (p < MAXF) b_list[p] = v * 4 + 3; }
        }
    }
    __syncthreads();

    const int wn = min(w_cnt, MAXF);
    const int bn = min(b_cnt, MAXF);

    // ---- Phase 2: gather-sum ft_w columns, 4-wide batches for ILP ----
    const float bias = ft_b[tid];
    float wacc = bias;
    float bacc = bias;
    if (TRANSPOSED) {
        const float* col = ftw + tid;
        int k = 0;
        for (; k + 4 <= wn; k += 4) {
            const int j0 = w_list[k], j1 = w_list[k + 1], j2 = w_list[k + 2], j3 = w_list[k + 3];
            const float f0 = col[(size_t)j0 * H0];
            const float f1 = col[(size_t)j1 * H0];
            const float f2 = col[(size_t)j2 * H0];
            const float f3 = col[(size_t)j3 * H0];
            wacc += (f0 + f1) + (f2 + f3);
        }
        for (; k < wn; ++k) wacc += col[(size_t)w_list[k] * H0];
        k = 0;
        for (; k + 4 <= bn; k += 4) {
            const int j0 = b_list[k], j1 = b_list[k + 1], j2 = b_list[k + 2], j3 = b_list[k + 3];
            const float f0 = col[(size_t)j0 * H0];
            const float f1 = col[(size_t)j1 * H0];
            const float f2 = col[(size_t)j2 * H0];
            const float f3 = col[(size_t)j3 * H0];
            bacc += (f0 + f1) + (f2 + f3);
        }
        for (; k < bn; ++k) bacc += col[(size_t)b_list[k] * H0];
    } else {
        const float* row = ftw + (size_t)tid * NIN;
        for (int k = 0; k < wn; ++k) wacc += row[w_list[k]];
        for (int k = 0; k < bn; ++k) bacc += row[b_list[k]];
    }
    const float ow = fminf(fmaxf(wacc, 0.f), 1.f);
    const float ob = fminf(fmaxf(bacc, 0.f), 1.f);
    const bool sd = (side[s] != 0);
    sh_o0[tid]       = sd ? ow : ob;
    sh_o0[256 + tid] = sd ? ob : ow;
    __syncthreads();

    // ---- l1: (32,512) @ o0 ; 8 threads per output row, p-staggered reads ----
    {
        const int o = tid >> 3;   // 0..31
        const int p = tid & 7;    // 0..7
        const float4* wp = (const float4*)(l1_w + (o * 512 + p * 64));
        const float4* xp = (const float4*)(sh_o0 + p * 64);
        float sum = 0.f;
#pragma unroll
        for (int i = 0; i < 16; ++i) {
            const int v = (2 * p + i) & 15;   // stagger start by p: banks spread
            float4 w4 = wp[v];
            float4 x4 = xp[v];
            sum += w4.x * x4.x + w4.y * x4.y + w4.z * x4.z + w4.w * x4.w;
        }
        sum += __shfl_down(sum, 4, 8);
        sum += __shfl_down(sum, 2, 8);
        sum += __shfl_down(sum, 1, 8);
        if (p == 0) sh_o1[o] = fminf(fmaxf(sum + l1_b[o], 0.f), 1.f);
    }
    __syncthreads();

    // ---- l2: (32,32) ----
    if (tid < 32) {
        float sum = 0.f;
#pragma unroll
        for (int k = 0; k < 32; ++k) sum += l2_w[tid * 32 + k] * sh_o1[k];
        sh_o2[tid] = fminf(fmaxf(sum + l2_b[tid], 0.f), 1.f);
    }
    __syncthreads();

    // ---- l3 + sigmoid ----
    if (tid < 32) {
        float p = l3_w[tid] * sh_o2[tid];
        p += __shfl_down(p, 16, 32);
        p += __shfl_down(p, 8, 32);
        p += __shfl_down(p, 4, 32);
        p += __shfl_down(p, 2, 32);
        p += __shfl_down(p, 1, 32);
        if (tid == 0) {
            const float o3  = (p + l3_b[0]) * 300.0f;
            const float sig = 1.0f / (1.0f + expf(-o3 / 200.0f));
            out[s] = sig;
        }
    }
}

extern "C" void kernel_launch(void* const* d_in, const int* in_sizes, int n_in,
                              void* d_out, int out_size, void* d_ws, size_t ws_size,
                              hipStream_t stream) {
    const float* white = (const float*)d_in[0];
    const float* black = (const float*)d_in[1];
    const int*   side  = (const int*)d_in[2];
    const float* ft_w  = (const float*)d_in[3];
    const float* ft_b  = (const float*)d_in[4];
    const float* l1_w  = (const float*)d_in[5];
    const float* l1_b  = (const float*)d_in[6];
    const float* l2_w  = (const float*)d_in[7];
    const float* l2_b  = (const float*)d_in[8];
    const float* l3_w  = (const float*)d_in[9];
    const float* l3_b  = (const float*)d_in[10];
    float*       out   = (float*)d_out;

    const int B = in_sizes[2];  // 8192
    const size_t t_bytes = (size_t)NIN * H0 * sizeof(float);  // 12.6 MB

    if (ws_size >= t_bytes) {
        float* ftw_t = (float*)d_ws;
        hipLaunchKernelGGL(transpose_ftw, dim3(NIN / 32, H0 / 32), dim3(32, 8), 0, stream,
                           ft_w, ftw_t);
        hipLaunchKernelGGL((nnue_kernel<true>), dim3(B), dim3(256), 0, stream,
                           white, black, side, ftw_t, ft_b, l1_w, l1_b, l2_w, l2_b, l3_w, l3_b, out);
    } else {
        hipLaunchKernelGGL((nnue_kernel<false>), dim3(B), dim3(256), 0, stream,
                           white, black, side, ft_w, ft_b, l1_w, l1_b, l2_w, l2_b, l3_w, l3_b, out);
    }
}